// Round 17
// baseline (115.117 us; speedup 1.0000x reference)
//
#include <hip/hip_runtime.h>
#include <math.h>

typedef __bf16 bf16x8 __attribute__((ext_vector_type(8)));
typedef float  f32x4  __attribute__((ext_vector_type(4)));
typedef float  f32x16 __attribute__((ext_vector_type(16)));
typedef unsigned short u16x8 __attribute__((ext_vector_type(8)));
typedef unsigned short u16x4 __attribute__((ext_vector_type(4)));

#define D_MODEL 1024
#define QDIM    64
#define HEADS   16
#define BATCH   2
#define SEQ     2048
#define M_ROWS  (BATCH*SEQ)        /* 4096 */
#define NCAT    (HEADS*3*QDIM)     /* 3072 */

__device__ __forceinline__ unsigned short f2bf(float f) {
    unsigned int u = __float_as_uint(f);
    u += 0x7fffu + ((u >> 16) & 1u);
    return (unsigned short)(u >> 16);
}

// async global->LDS, 16B per lane. LDS dest = wave-uniform base + lane*16.
__device__ __forceinline__ void gl16(const unsigned short* g, unsigned short* l) {
    __builtin_amdgcn_global_load_lds(
        (const __attribute__((address_space(1))) unsigned int*)g,
        (__attribute__((address_space(3))) unsigned int*)l, 16, 0, 0);
}

// ------- merged prep: blocks 0..2047 cvt xi->bf16; 2048..2815 WcatT; 2816..3071 WoT -------
__global__ __launch_bounds__(256) void k_prep_w(const float* __restrict__ xi,
                                                const float* __restrict__ Wq,
                                                const float* __restrict__ Wk,
                                                const float* __restrict__ Wv,
                                                const float* __restrict__ bq,
                                                const float* __restrict__ bk,
                                                const float* __restrict__ bv,
                                                const float* __restrict__ Wo,
                                                unsigned short* __restrict__ xi_bf,
                                                unsigned short* __restrict__ WcatT,
                                                float* __restrict__ bcat,
                                                unsigned short* __restrict__ WoT,
                                                float qscale) {
    int tid = threadIdx.x;
    if (blockIdx.x < 2048) {
        int i = (blockIdx.x * 256 + tid) * 8;
        f32x4 a = *(const f32x4*)(xi + i);
        f32x4 b = *(const f32x4*)(xi + i + 4);
        u16x8 o;
        o[0]=f2bf(a[0]); o[1]=f2bf(a[1]); o[2]=f2bf(a[2]); o[3]=f2bf(a[3]);
        o[4]=f2bf(b[0]); o[5]=f2bf(b[1]); o[6]=f2bf(b[2]); o[7]=f2bf(b[3]);
        *(u16x8*)(xi_bf + i) = o;
        return;
    }
    __shared__ float t[64][65];
    int dr = tid >> 2, qc = (tid & 3) * 16;
    if (blockIdx.x < 2816) {
        int blk = blockIdx.x - 2048;
        int dt = blk & 15, h = (blk >> 4) & 15, s = blk >> 8;
        const float* W = (s == 0) ? Wq : (s == 1) ? Wk : Wv;
        float sc = (s == 0) ? qscale : 1.0f;
        const float* src = W + (size_t)h * (D_MODEL * QDIM) + (size_t)(dt * 64 + dr) * QDIM + qc;
#pragma unroll
        for (int j = 0; j < 4; ++j) {
            f32x4 v = *(const f32x4*)(src + j * 4);
            t[dr][qc + j * 4 + 0] = v[0]; t[dr][qc + j * 4 + 1] = v[1];
            t[dr][qc + j * 4 + 2] = v[2]; t[dr][qc + j * 4 + 3] = v[3];
        }
        __syncthreads();
        int q = tid >> 2, dc = (tid & 3) * 16;
        unsigned short* dst = WcatT + (size_t)(h * 192 + s * 64 + q) * D_MODEL + dt * 64 + dc;
#pragma unroll
        for (int j = 0; j < 2; ++j) {
            u16x8 o;
#pragma unroll
            for (int e = 0; e < 8; ++e) o[e] = f2bf(t[dc + j * 8 + e][q] * sc);
            *(u16x8*)(dst + j * 8) = o;
        }
        if (dt == 0 && tid < 64) {
            const float* bb = (s == 0) ? bq : (s == 1) ? bk : bv;
            bcat[h * 192 + s * 64 + tid] = bb[h * QDIM + tid] * sc;
        }
    } else {
        int blk = blockIdx.x - 2816;
        int ct = blk & 15, rt = blk >> 4;
        const float* src = Wo + (size_t)(rt * 64 + dr) * D_MODEL + ct * 64 + qc;
#pragma unroll
        for (int j = 0; j < 4; ++j) {
            f32x4 v = *(const f32x4*)(src + j * 4);
            t[dr][qc + j * 4 + 0] = v[0]; t[dr][qc + j * 4 + 1] = v[1];
            t[dr][qc + j * 4 + 2] = v[2]; t[dr][qc + j * 4 + 3] = v[3];
        }
        __syncthreads();
        int q = tid >> 2, dc = (tid & 3) * 16;
        unsigned short* dst = WoT + (size_t)(ct * 64 + q) * D_MODEL + rt * 64 + dc;
#pragma unroll
        for (int j = 0; j < 2; ++j) {
            u16x8 o;
#pragma unroll
            for (int e = 0; e < 8; ++e) o[e] = f2bf(t[dc + j * 8 + e][q]);
            *(u16x8*)(dst + j * 8) = o;
        }
    }
}

// ---------------- GEMM: 128x128 tile, BK=32, 3-buf ring (48KB -> 3 blocks/CU), counted vmcnt ----------------
template<bool FUSED>
__global__ __launch_bounds__(256) void k_gemm(const unsigned short* __restrict__ A,
                                              const unsigned short* __restrict__ BT,
                                              const float* __restrict__ bias,
                                              void* __restrict__ Cout,
                                              unsigned short* __restrict__ kfrag,
                                              unsigned short* __restrict__ vfrag,
                                              int N, int Kd) {
    __shared__ __align__(16) unsigned char smem[49152];   // 3 bufs x 16KB
    const int tid = threadIdx.x;
    const int lane = tid & 63, w = tid >> 6;
    const int g = lane >> 4, c = lane & 15;
    int nwg = gridDim.x * gridDim.y;
    int bid = blockIdx.y * gridDim.x + blockIdx.x;
    int sw = (bid & 7) * (nwg >> 3) + (bid >> 3);
    int bx = sw % gridDim.x, by = sw / gridDim.x;
    const int m0 = by * 128, n0 = bx * 128;
    const int wm = (w >> 1) * 64, wn = (w & 1) * 64;
    f32x4 acc[4][4] = {};

    const int srow = w * 16 + (lane >> 2);
    const int scol = ((lane & 3) ^ ((lane >> 3) & 3)) * 8;
    const unsigned short* pA0 = A  + (size_t)(m0 + srow) * Kd + scol;
    const unsigned short* pA1 = pA0 + (size_t)64 * Kd;
    const unsigned short* pB0 = BT + (size_t)(n0 + srow) * Kd + scol;
    const unsigned short* pB1 = pB0 + (size_t)64 * Kd;
    const int kc = (c >> 1) & 3;
    const int aoff = (wm + c) * 64 + ((g ^ kc) * 16);
    const int boff = (wn + c) * 64 + ((g ^ kc) * 16);

#define STAGE(buf)                                                                   \
    {                                                                                \
        unsigned short* lb = (unsigned short*)(smem + (buf) * 16384) + w * 512;      \
        gl16(pA0, lb);                                                               \
        gl16(pA1, lb + 2048);                                                        \
        gl16(pB0, lb + 4096);                                                        \
        gl16(pB1, lb + 6144);                                                        \
        pA0 += 32; pA1 += 32; pB0 += 32; pB1 += 32;                                  \
    }

#define COMPUTE(buf)                                                                 \
    {                                                                                \
        const unsigned char* Ab = smem + (buf) * 16384;                              \
        const unsigned char* Bb = Ab + 8192;                                         \
        bf16x8 af[4], bfr[4];                                                        \
        _Pragma("unroll") for (int mf = 0; mf < 4; ++mf)                             \
            af[mf] = *(const bf16x8*)(Ab + mf * 1024 + aoff);                        \
        _Pragma("unroll") for (int nf = 0; nf < 4; ++nf)                             \
            bfr[nf] = *(const bf16x8*)(Bb + nf * 1024 + boff);                       \
        __builtin_amdgcn_s_setprio(1);                                               \
        _Pragma("unroll") for (int mf = 0; mf < 4; ++mf)                             \
            _Pragma("unroll") for (int nf = 0; nf < 4; ++nf)                         \
                acc[mf][nf] = __builtin_amdgcn_mfma_f32_16x16x32_bf16(               \
                    af[mf], bfr[nf], acc[mf][nf], 0, 0, 0);                          \
        __builtin_amdgcn_s_setprio(0);                                               \
    }

    const int nt = Kd >> 5;   // 32
    STAGE(0); STAGE(1);
    int sb = 2, cb = 0;
    for (int t = 0; t < nt - 2; ++t) {
        STAGE(sb);
        sb = (sb == 2) ? 0 : sb + 1;
        asm volatile("s_waitcnt vmcnt(8)" ::: "memory");
        __builtin_amdgcn_s_barrier();
        __builtin_amdgcn_sched_barrier(0);
        COMPUTE(cb);
        cb = (cb == 2) ? 0 : cb + 1;
        __builtin_amdgcn_sched_barrier(0);
        __builtin_amdgcn_s_barrier();
    }
    asm volatile("s_waitcnt vmcnt(4)" ::: "memory");
    __builtin_amdgcn_s_barrier();
    __builtin_amdgcn_sched_barrier(0);
    COMPUTE(cb);
    cb = (cb == 2) ? 0 : cb + 1;
    __builtin_amdgcn_sched_barrier(0);
    __builtin_amdgcn_s_barrier();
    asm volatile("s_waitcnt vmcnt(0)" ::: "memory");
    __builtin_amdgcn_s_barrier();
    __builtin_amdgcn_sched_barrier(0);
    COMPUTE(cb);
#undef STAGE
#undef COMPUTE

#pragma unroll
    for (int mf = 0; mf < 4; ++mf) {
        const int row0 = m0 + wm + mf * 16 + 4 * g;
        const int bb_  = row0 >> 11;
        const int s_   = row0 & 2047;
        const int tile = s_ >> 6;
        const int krb  = s_ & 63;
#pragma unroll
        for (int nf = 0; nf < 4; ++nf) {
            int col = n0 + wn + nf * 16 + c;
            float bv = bias[col];
            if (!FUSED) {
#pragma unroll
                for (int r = 0; r < 4; ++r)
                    ((float*)Cout)[(size_t)(row0 + r) * N + col] = acc[mf][nf][r] + bv;
            } else {
                unsigned short q0 = f2bf(acc[mf][nf][0] + bv);
                unsigned short q1 = f2bf(acc[mf][nf][1] + bv);
                unsigned short q2 = f2bf(acc[mf][nf][2] + bv);
                unsigned short q3 = f2bf(acc[mf][nf][3] + bv);
                int h   = col / 192;
                int rem = col - h * 192;
                int kind = rem >> 6;
                int d   = rem & 63;
                if (kind == 0) {
                    unsigned short* p = (unsigned short*)Cout + (size_t)row0 * NCAT + col;
                    p[0] = q0; p[NCAT] = q1; p[2 * NCAT] = q2; p[3 * NCAT] = q3;
                } else {
                    size_t obase = (size_t)(bb_ * 512 + h * 32 + tile) * 4096;
                    if (kind == 1) {
                        int f  = (krb >> 5) * 4 + (d >> 4);
                        int hi = (d >> 3) & 1;
                        unsigned short* p = kfrag + obase + f * 512 + hi * 256 +
                                            (size_t)(krb & 31) * 8 + (d & 7);
                        p[0] = q0; p[8] = q1; p[16] = q2; p[24] = q3;
                    } else {
                        int f  = (krb >> 5) * 4 + ((krb >> 4) & 1) * 2 + (d >> 5);
                        int hi = (krb >> 3) & 1;
                        u16x4 pk = {q0, q1, q2, q3};
                        *(u16x4*)(vfrag + obase + f * 512 + hi * 256 +
                                  (size_t)(d & 31) * 8 + (krb & 7)) = pk;
                    }
                }
            }
        }
    }
}

// ---------------- flash attention: register pipeline (exp2, hoisted zero, split rsum) ----------------
__global__ __launch_bounds__(256) void k_attn(const unsigned short* __restrict__ qkv,
                                              const unsigned short* __restrict__ kfrag,
                                              const unsigned short* __restrict__ vfrag,
                                              unsigned short* __restrict__ attn) {
    int bid = blockIdx.x;
    int blk = (bid & 7) * 128 + (bid >> 3);   // XCD-chunked: 4 heads per XCD
    int qt = blk & 31, h = (blk >> 5) & 15, b = blk >> 9;
    int tid = threadIdx.x, w = tid >> 6, lane = tid & 63;
    int l31 = lane & 31, hi = lane >> 5;
    int qh = w & 1, kh = w >> 1;

    __shared__ float red[4096];   // [64 q][64 v] f32 = 16 KB (epilogue only)
    __shared__ float rsb[128];    // [2 kh][2 qh][32 q]

    const int qbase = b * SEQ + qt * 64;
    const unsigned short* qrow = qkv + (size_t)(qbase + qh * 32 + l31) * NCAT + h * 192;
    bf16x8 qf0 = *(const bf16x8*)(qrow + 0 * 16 + hi * 8);
    bf16x8 qf1 = *(const bf16x8*)(qrow + 1 * 16 + hi * 8);
    bf16x8 qf2 = *(const bf16x8*)(qrow + 2 * 16 + hi * 8);
    bf16x8 qf3 = *(const bf16x8*)(qrow + 3 * 16 + hi * 8);

    f32x16 o0 = {}, o1 = {};
    const f32x16 z16 = {};        // loop-invariant zero C-in for QK^T
    f32x4 rsv = {};               // 4 independent rowsum accumulators

    const size_t fb = (size_t)(b * 512 + h * 32) * 4096 + (size_t)(kh * 4) * 512 + lane * 8;
    const unsigned short* kp = kfrag + fb;
    const unsigned short* vp = vfrag + fb;

    bf16x8 aK0, aK1, aK2, aK3, aV0, aV1, aV2, aV3;
    bf16x8 bK0, bK1, bK2, bK3, bV0, bV1, bV2, bV3;

#define LOADT(K0, K1, K2, K3, V0, V1, V2, V3)                   \
    {                                                           \
        K0 = *(const bf16x8*)(kp);                              \
        K1 = *(const bf16x8*)(kp + 512);                        \
        K2 = *(const bf16x8*)(kp + 1024);                       \
        K3 = *(const bf16x8*)(kp + 1536);                       \
        V0 = *(const bf16x8*)(vp);                              \
        V1 = *(const bf16x8*)(vp + 512);                        \
        V2 = *(const bf16x8*)(vp + 1024);                       \
        V3 = *(const bf16x8*)(vp + 1536);                       \
        kp += 4096; vp += 4096;                                 \
    }

#define COMPUTE(K0, K1, K2, K3, V0, V1, V2, V3)                                       \
    {                                                                                 \
        f32x16 st = __builtin_amdgcn_mfma_f32_32x32x16_bf16(K0, qf0, z16, 0, 0, 0);   \
        st = __builtin_amdgcn_mfma_f32_32x32x16_bf16(K1, qf1, st, 0, 0, 0);           \
        st = __builtin_amdgcn_mfma_f32_32x32x16_bf16(K2, qf2, st, 0, 0, 0);           \
        st = __builtin_amdgcn_mfma_f32_32x32x16_bf16(K3, qf3, st, 0, 0, 0);           \
        _Pragma("unroll") for (int r = 0; r < 16; ++r) {                              \
            float p = __builtin_amdgcn_exp2f(st[r]);                                  \
            st[r] = p;                                                                \
            rsv[r & 3] += p;                                                          \
        }                                                                             \
        unsigned int d0, d1, d2, d3, d4, d5, d6, d7;                                  \
        asm("v_cvt_pk_bf16_f32 %0, %1, %2" : "=v"(d0) : "v"(st[0]),  "v"(st[1]));     \
        asm("v_cvt_pk_bf16_f32 %0, %1, %2" : "=v"(d1) : "v"(st[2]),  "v"(st[3]));     \
        asm("v_cvt_pk_bf16_f32 %0, %1, %2" : "=v"(d2) : "v"(st[4]),  "v"(st[5]));     \
        asm("v_cvt_pk_bf16_f32 %0, %1, %2" : "=v"(d3) : "v"(st[6]),  "v"(st[7]));     \
        asm("v_cvt_pk_bf16_f32 %0, %1, %2" : "=v"(d4) : "v"(st[8]),  "v"(st[9]));     \
        asm("v_cvt_pk_bf16_f32 %0, %1, %2" : "=v"(d5) : "v"(st[10]), "v"(st[11]));    \
        asm("v_cvt_pk_bf16_f32 %0, %1, %2" : "=v"(d6) : "v"(st[12]), "v"(st[13]));    \
        asm("v_cvt_pk_bf16_f32 %0, %1, %2" : "=v"(d7) : "v"(st[14]), "v"(st[15]));    \
        asm("v_permlane32_swap_b32 %0, %1" : "+v"(d0), "+v"(d2));                     \
        asm("v_permlane32_swap_b32 %0, %1" : "+v"(d1), "+v"(d3));                     \
        asm("v_permlane32_swap_b32 %0, %1" : "+v"(d4), "+v"(d6));                     \
        asm("v_permlane32_swap_b32 %0, %1" : "+v"(d5), "+v"(d7));                     \
        union { unsigned int u[4]; bf16x8 v; } pa0, pa1;                              \
        pa0.u[0] = d0; pa0.u[1] = d1; pa0.u[2] = d2; pa0.u[3] = d3;                   \
        pa1.u[0] = d4; pa1.u[1] = d5; pa1.u[2] = d6; pa1.u[3] = d7;                   \
        o0 = __builtin_amdgcn_mfma_f32_32x32x16_bf16(pa0.v, V0, o0, 0, 0, 0);         \
        o1 = __builtin_amdgcn_mfma_f32_32x32x16_bf16(pa0.v, V1, o1, 0, 0, 0);         \
        o0 = __builtin_amdgcn_mfma_f32_32x32x16_bf16(pa1.v, V2, o0, 0, 0, 0);         \
        o1 = __builtin_amdgcn_mfma_f32_32x32x16_bf16(pa1.v, V3, o1, 0, 0, 0);         \
    }

    LOADT(aK0, aK1, aK2, aK3, aV0, aV1, aV2, aV3);

    const int NT = SEQ / 64;   // 32, even
    for (int t = 0; t < NT; t += 2) {
        LOADT(bK0, bK1, bK2, bK3, bV0, bV1, bV2, bV3);
        COMPUTE(aK0, aK1, aK2, aK3, aV0, aV1, aV2, aV3);
        if (t + 2 < NT)
            LOADT(aK0, aK1, aK2, aK3, aV0, aV1, aV2, aV3);
        COMPUTE(bK0, bK1, bK2, bK3, bV0, bV1, bV2, bV3);
    }
#undef LOADT
#undef COMPUTE

    // ---- merge kh partials + normalize + store ----
    float rsum = (rsv[0] + rsv[1]) + (rsv[2] + rsv[3]);
    rsum += __shfl_xor(rsum, 32);
    if (kh == 1) {
#pragma unroll
        for (int r = 0; r < 16; ++r) {
            int q = (r & 3) + 8 * (r >> 2) + 4 * hi;
            red[(qh * 32 + q) * 64 + l31]      = o0[r];
            red[(qh * 32 + q) * 64 + 32 + l31] = o1[r];
        }
    }
    if (lane < 32) rsb[(kh * 2 + qh) * 32 + l31] = rsum;
    __syncthreads();
    if (kh == 0) {
#pragma unroll
        for (int r = 0; r < 16; ++r) {
            int q = (r & 3) + 8 * (r >> 2) + 4 * hi;
            float tot = rsb[qh * 32 + q] + rsb[(2 + qh) * 32 + q];
            float inv = 1.0f / tot;
            float v0e = (o0[r] + red[(qh * 32 + q) * 64 + l31]) * inv;
            float v1e = (o1[r] + red[(qh * 32 + q) * 64 + 32 + l31]) * inv;
            int row = qbase + qh * 32 + q;
            attn[(size_t)row * (HEADS * QDIM) + h * QDIM + l31]      = f2bf(v0e);
            attn[(size_t)row * (HEADS * QDIM) + h * QDIM + 32 + l31] = f2bf(v1e);
        }
    }
}

extern "C" void kernel_launch(void* const* d_in, const int* in_sizes, int n_in,
                              void* d_out, int out_size, void* d_ws, size_t ws_size,
                              hipStream_t stream) {
    const float* xi = (const float*)d_in[0];
    const float* Wq = (const float*)d_in[1];
    const float* bq = (const float*)d_in[2];
    const float* Wk = (const float*)d_in[3];
    const float* bk = (const float*)d_in[4];
    const float* Wv = (const float*)d_in[5];
    const float* bv = (const float*)d_in[6];
    const float* Wo = (const float*)d_in[7];
    const float* bo = (const float*)d_in[8];

    unsigned short* xi_bf = (unsigned short*)d_ws;
    unsigned short* WcatT = xi_bf + (size_t)M_ROWS * D_MODEL;
    unsigned short* WoT   = WcatT + (size_t)NCAT * D_MODEL;
    float*          bcat  = (float*)(WoT + (size_t)D_MODEL * D_MODEL);
    unsigned short* qkvc  = (unsigned short*)(bcat + NCAT);
    unsigned short* kfrag = qkvc + (size_t)M_ROWS * NCAT;
    unsigned short* vfrag = kfrag + (size_t)BATCH * HEADS * 32 * 4096;
    unsigned short* attnb = vfrag + (size_t)BATCH * HEADS * 32 * 4096;

    // fold softmax scale AND log2(e) into Q projection (attn uses exp2)
    float qscale = 1.4426950408889634f / sqrtf((float)SEQ);

    k_prep_w<<<3072, 256, 0, stream>>>(xi, Wq, Wk, Wv, bq, bk, bv, Wo,
                                       xi_bf, WcatT, bcat, WoT, qscale);

    k_gemm<true><<<dim3(NCAT / 128, M_ROWS / 128), 256, 0, stream>>>(
        xi_bf, WcatT, bcat, (void*)qkvc, kfrag, vfrag, NCAT, D_MODEL);

    k_attn<<<BATCH * HEADS * (SEQ / 64), 256, 0, stream>>>(qkvc, kfrag, vfrag, attnb);

    k_gemm<false><<<dim3(D_MODEL / 128, M_ROWS / 128), 256, 0, stream>>>(
        attnb, WoT, bo, d_out, nullptr, nullptr, D_MODEL, D_MODEL);
}

// Round 18
// 114.262 us; speedup vs baseline: 1.0075x; 1.0075x over previous
//
#include <hip/hip_runtime.h>
#include <math.h>

typedef __bf16 bf16x8 __attribute__((ext_vector_type(8)));
typedef float  f32x4  __attribute__((ext_vector_type(4)));
typedef float  f32x16 __attribute__((ext_vector_type(16)));
typedef unsigned short u16x8 __attribute__((ext_vector_type(8)));
typedef unsigned short u16x4 __attribute__((ext_vector_type(4)));

#define D_MODEL 1024
#define QDIM    64
#define HEADS   16
#define BATCH   2
#define SEQ     2048
#define M_ROWS  (BATCH*SEQ)        /* 4096 */
#define NCAT    (HEADS*3*QDIM)     /* 3072 */

__device__ __forceinline__ unsigned short f2bf(float f) {
    unsigned int u = __float_as_uint(f);
    u += 0x7fffu + ((u >> 16) & 1u);
    return (unsigned short)(u >> 16);
}

// async global->LDS, 16B per lane. LDS dest = wave-uniform base + lane*16.
__device__ __forceinline__ void gl16(const unsigned short* g, unsigned short* l) {
    __builtin_amdgcn_global_load_lds(
        (const __attribute__((address_space(1))) unsigned int*)g,
        (__attribute__((address_space(3))) unsigned int*)l, 16, 0, 0);
}

// ------- merged prep: blocks 0..2047 cvt xi->bf16; 2048..2815 WcatT; 2816..3071 WoT -------
__global__ __launch_bounds__(256) void k_prep_w(const float* __restrict__ xi,
                                                const float* __restrict__ Wq,
                                                const float* __restrict__ Wk,
                                                const float* __restrict__ Wv,
                                                const float* __restrict__ bq,
                                                const float* __restrict__ bk,
                                                const float* __restrict__ bv,
                                                const float* __restrict__ Wo,
                                                unsigned short* __restrict__ xi_bf,
                                                unsigned short* __restrict__ WcatT,
                                                float* __restrict__ bcat,
                                                unsigned short* __restrict__ WoT,
                                                float qscale) {
    int tid = threadIdx.x;
    if (blockIdx.x < 2048) {
        int i = (blockIdx.x * 256 + tid) * 8;
        f32x4 a = *(const f32x4*)(xi + i);
        f32x4 b = *(const f32x4*)(xi + i + 4);
        u16x8 o;
        o[0]=f2bf(a[0]); o[1]=f2bf(a[1]); o[2]=f2bf(a[2]); o[3]=f2bf(a[3]);
        o[4]=f2bf(b[0]); o[5]=f2bf(b[1]); o[6]=f2bf(b[2]); o[7]=f2bf(b[3]);
        *(u16x8*)(xi_bf + i) = o;
        return;
    }
    __shared__ float t[64][65];
    int dr = tid >> 2, qc = (tid & 3) * 16;
    if (blockIdx.x < 2816) {
        int blk = blockIdx.x - 2048;
        int dt = blk & 15, h = (blk >> 4) & 15, s = blk >> 8;
        const float* W = (s == 0) ? Wq : (s == 1) ? Wk : Wv;
        float sc = (s == 0) ? qscale : 1.0f;
        const float* src = W + (size_t)h * (D_MODEL * QDIM) + (size_t)(dt * 64 + dr) * QDIM + qc;
#pragma unroll
        for (int j = 0; j < 4; ++j) {
            f32x4 v = *(const f32x4*)(src + j * 4);
            t[dr][qc + j * 4 + 0] = v[0]; t[dr][qc + j * 4 + 1] = v[1];
            t[dr][qc + j * 4 + 2] = v[2]; t[dr][qc + j * 4 + 3] = v[3];
        }
        __syncthreads();
        int q = tid >> 2, dc = (tid & 3) * 16;
        unsigned short* dst = WcatT + (size_t)(h * 192 + s * 64 + q) * D_MODEL + dt * 64 + dc;
#pragma unroll
        for (int j = 0; j < 2; ++j) {
            u16x8 o;
#pragma unroll
            for (int e = 0; e < 8; ++e) o[e] = f2bf(t[dc + j * 8 + e][q] * sc);
            *(u16x8*)(dst + j * 8) = o;
        }
        if (dt == 0 && tid < 64) {
            const float* bb = (s == 0) ? bq : (s == 1) ? bk : bv;
            bcat[h * 192 + s * 64 + tid] = bb[h * QDIM + tid] * sc;
        }
    } else {
        int blk = blockIdx.x - 2816;
        int ct = blk & 15, rt = blk >> 4;
        const float* src = Wo + (size_t)(rt * 64 + dr) * D_MODEL + ct * 64 + qc;
#pragma unroll
        for (int j = 0; j < 4; ++j) {
            f32x4 v = *(const f32x4*)(src + j * 4);
            t[dr][qc + j * 4 + 0] = v[0]; t[dr][qc + j * 4 + 1] = v[1];
            t[dr][qc + j * 4 + 2] = v[2]; t[dr][qc + j * 4 + 3] = v[3];
        }
        __syncthreads();
        int q = tid >> 2, dc = (tid & 3) * 16;
        unsigned short* dst = WoT + (size_t)(ct * 64 + q) * D_MODEL + rt * 64 + dc;
#pragma unroll
        for (int j = 0; j < 2; ++j) {
            u16x8 o;
#pragma unroll
            for (int e = 0; e < 8; ++e) o[e] = f2bf(t[dc + j * 8 + e][q]);
            *(u16x8*)(dst + j * 8) = o;
        }
    }
}

// ---------------- GEMM: 128x128 tile, BK=32, 3-buf ring (48KB -> 3 blocks/CU), counted vmcnt ----------------
// Stage tile t+2 while computing tile t; vmcnt(8) retires tile t's 4 loads.
// FUSED=true (GEMM1): epilogue routes Q cols -> qkvc, K/V cols -> fragment buffers.
template<bool FUSED>
__global__ __launch_bounds__(256) void k_gemm(const unsigned short* __restrict__ A,
                                              const unsigned short* __restrict__ BT,
                                              const float* __restrict__ bias,
                                              void* __restrict__ Cout,
                                              unsigned short* __restrict__ kfrag,
                                              unsigned short* __restrict__ vfrag,
                                              int N, int Kd) {
    __shared__ __align__(16) unsigned char smem[49152];   // 3 bufs x 16KB
    const int tid = threadIdx.x;
    const int lane = tid & 63, w = tid >> 6;
    const int g = lane >> 4, c = lane & 15;
    int nwg = gridDim.x * gridDim.y;
    int bid = blockIdx.y * gridDim.x + blockIdx.x;
    int sw = (bid & 7) * (nwg >> 3) + (bid >> 3);
    int bx = sw % gridDim.x, by = sw / gridDim.x;
    const int m0 = by * 128, n0 = bx * 128;
    const int wm = (w >> 1) * 64, wn = (w & 1) * 64;
    f32x4 acc[4][4] = {};

    const int srow = w * 16 + (lane >> 2);
    const int scol = ((lane & 3) ^ ((lane >> 3) & 3)) * 8;
    const unsigned short* pA0 = A  + (size_t)(m0 + srow) * Kd + scol;
    const unsigned short* pA1 = pA0 + (size_t)64 * Kd;
    const unsigned short* pB0 = BT + (size_t)(n0 + srow) * Kd + scol;
    const unsigned short* pB1 = pB0 + (size_t)64 * Kd;
    const int kc = (c >> 1) & 3;
    const int aoff = (wm + c) * 64 + ((g ^ kc) * 16);
    const int boff = (wn + c) * 64 + ((g ^ kc) * 16);

#define STAGE(buf)                                                                   \
    {                                                                                \
        unsigned short* lb = (unsigned short*)(smem + (buf) * 16384) + w * 512;      \
        gl16(pA0, lb);                                                               \
        gl16(pA1, lb + 2048);                                                        \
        gl16(pB0, lb + 4096);                                                        \
        gl16(pB1, lb + 6144);                                                        \
        pA0 += 32; pA1 += 32; pB0 += 32; pB1 += 32;                                  \
    }

#define COMPUTE(buf)                                                                 \
    {                                                                                \
        const unsigned char* Ab = smem + (buf) * 16384;                              \
        const unsigned char* Bb = Ab + 8192;                                         \
        bf16x8 af[4], bfr[4];                                                        \
        _Pragma("unroll") for (int mf = 0; mf < 4; ++mf)                             \
            af[mf] = *(const bf16x8*)(Ab + mf * 1024 + aoff);                        \
        _Pragma("unroll") for (int nf = 0; nf < 4; ++nf)                             \
            bfr[nf] = *(const bf16x8*)(Bb + nf * 1024 + boff);                       \
        __builtin_amdgcn_s_setprio(1);                                               \
        _Pragma("unroll") for (int mf = 0; mf < 4; ++mf)                             \
            _Pragma("unroll") for (int nf = 0; nf < 4; ++nf)                         \
                acc[mf][nf] = __builtin_amdgcn_mfma_f32_16x16x32_bf16(               \
                    af[mf], bfr[nf], acc[mf][nf], 0, 0, 0);                          \
        __builtin_amdgcn_s_setprio(0);                                               \
    }

    const int nt = Kd >> 5;   // 32
    STAGE(0); STAGE(1);
    int sb = 2, cb = 0;
    for (int t = 0; t < nt - 2; ++t) {
        STAGE(sb);
        sb = (sb == 2) ? 0 : sb + 1;
        asm volatile("s_waitcnt vmcnt(8)" ::: "memory");
        __builtin_amdgcn_s_barrier();
        __builtin_amdgcn_sched_barrier(0);
        COMPUTE(cb);
        cb = (cb == 2) ? 0 : cb + 1;
        __builtin_amdgcn_sched_barrier(0);
        __builtin_amdgcn_s_barrier();
    }
    asm volatile("s_waitcnt vmcnt(4)" ::: "memory");
    __builtin_amdgcn_s_barrier();
    __builtin_amdgcn_sched_barrier(0);
    COMPUTE(cb);
    cb = (cb == 2) ? 0 : cb + 1;
    __builtin_amdgcn_sched_barrier(0);
    __builtin_amdgcn_s_barrier();
    asm volatile("s_waitcnt vmcnt(0)" ::: "memory");
    __builtin_amdgcn_s_barrier();
    __builtin_amdgcn_sched_barrier(0);
    COMPUTE(cb);
#undef STAGE
#undef COMPUTE

#pragma unroll
    for (int mf = 0; mf < 4; ++mf) {
        const int row0 = m0 + wm + mf * 16 + 4 * g;
        const int bb_  = row0 >> 11;          // batch (FUSED)
        const int s_   = row0 & 2047;
        const int tile = s_ >> 6;
        const int krb  = s_ & 63;             // row within kv-tile (r adds 0..3, no 32-crossing)
#pragma unroll
        for (int nf = 0; nf < 4; ++nf) {
            int col = n0 + wn + nf * 16 + c;
            float bv = bias[col];
            if (!FUSED) {
#pragma unroll
                for (int r = 0; r < 4; ++r)
                    ((float*)Cout)[(size_t)(row0 + r) * N + col] = acc[mf][nf][r] + bv;
            } else {
                unsigned short q0 = f2bf(acc[mf][nf][0] + bv);
                unsigned short q1 = f2bf(acc[mf][nf][1] + bv);
                unsigned short q2 = f2bf(acc[mf][nf][2] + bv);
                unsigned short q3 = f2bf(acc[mf][nf][3] + bv);
                int h   = col / 192;
                int rem = col - h * 192;
                int kind = rem >> 6;          // lane-uniform per (mf,nf)
                int d   = rem & 63;
                if (kind == 0) {
                    unsigned short* p = (unsigned short*)Cout + (size_t)row0 * NCAT + col;
                    p[0] = q0; p[NCAT] = q1; p[2 * NCAT] = q2; p[3 * NCAT] = q3;
                } else {
                    size_t obase = (size_t)(bb_ * 512 + h * 32 + tile) * 4096;
                    if (kind == 1) {
                        int f  = (krb >> 5) * 4 + (d >> 4);
                        int hi = (d >> 3) & 1;
                        unsigned short* p = kfrag + obase + f * 512 + hi * 256 +
                                            (size_t)(krb & 31) * 8 + (d & 7);
                        p[0] = q0; p[8] = q1; p[16] = q2; p[24] = q3;
                    } else {
                        int f  = (krb >> 5) * 4 + ((krb >> 4) & 1) * 2 + (d >> 5);
                        int hi = (krb >> 3) & 1;
                        u16x4 pk = {q0, q1, q2, q3};
                        *(u16x4*)(vfrag + obase + f * 512 + hi * 256 +
                                  (size_t)(d & 31) * 8 + (krb & 7)) = pk;
                    }
                }
            }
        }
    }
}

// ---------------- flash attention: r11-proven register pipeline (exp2) ----------------
__global__ __launch_bounds__(256) void k_attn(const unsigned short* __restrict__ qkv,
                                              const unsigned short* __restrict__ kfrag,
                                              const unsigned short* __restrict__ vfrag,
                                              unsigned short* __restrict__ attn) {
    int bid = blockIdx.x;
    int blk = (bid & 7) * 128 + (bid >> 3);   // XCD-chunked: 4 heads per XCD
    int qt = blk & 31, h = (blk >> 5) & 15, b = blk >> 9;
    int tid = threadIdx.x, w = tid >> 6, lane = tid & 63;
    int l31 = lane & 31, hi = lane >> 5;
    int qh = w & 1, kh = w >> 1;

    __shared__ float red[4096];   // [64 q][64 v] f32 = 16 KB (epilogue only)
    __shared__ float rsb[128];    // [2 kh][2 qh][32 q]

    const int qbase = b * SEQ + qt * 64;
    const unsigned short* qrow = qkv + (size_t)(qbase + qh * 32 + l31) * NCAT + h * 192;
    bf16x8 qf0 = *(const bf16x8*)(qrow + 0 * 16 + hi * 8);
    bf16x8 qf1 = *(const bf16x8*)(qrow + 1 * 16 + hi * 8);
    bf16x8 qf2 = *(const bf16x8*)(qrow + 2 * 16 + hi * 8);
    bf16x8 qf3 = *(const bf16x8*)(qrow + 3 * 16 + hi * 8);

    f32x16 o0 = {}, o1 = {};
    float rsum = 0.f;

    const size_t fb = (size_t)(b * 512 + h * 32) * 4096 + (size_t)(kh * 4) * 512 + lane * 8;
    const unsigned short* kp = kfrag + fb;
    const unsigned short* vp = vfrag + fb;

    bf16x8 aK0, aK1, aK2, aK3, aV0, aV1, aV2, aV3;
    bf16x8 bK0, bK1, bK2, bK3, bV0, bV1, bV2, bV3;

#define LOADT(K0, K1, K2, K3, V0, V1, V2, V3)                   \
    {                                                           \
        K0 = *(const bf16x8*)(kp);                              \
        K1 = *(const bf16x8*)(kp + 512);                        \
        K2 = *(const bf16x8*)(kp + 1024);                       \
        K3 = *(const bf16x8*)(kp + 1536);                       \
        V0 = *(const bf16x8*)(vp);                              \
        V1 = *(const bf16x8*)(vp + 512);                        \
        V2 = *(const bf16x8*)(vp + 1024);                       \
        V3 = *(const bf16x8*)(vp + 1536);                       \
        kp += 4096; vp += 4096;                                 \
    }

#define COMPUTE(K0, K1, K2, K3, V0, V1, V2, V3)                                       \
    {                                                                                 \
        f32x16 st = {};                                                               \
        st = __builtin_amdgcn_mfma_f32_32x32x16_bf16(K0, qf0, st, 0, 0, 0);           \
        st = __builtin_amdgcn_mfma_f32_32x32x16_bf16(K1, qf1, st, 0, 0, 0);           \
        st = __builtin_amdgcn_mfma_f32_32x32x16_bf16(K2, qf2, st, 0, 0, 0);           \
        st = __builtin_amdgcn_mfma_f32_32x32x16_bf16(K3, qf3, st, 0, 0, 0);           \
        _Pragma("unroll") for (int r = 0; r < 16; ++r) {                              \
            float p = __builtin_amdgcn_exp2f(st[r]);                                  \
            st[r] = p;                                                                \
            rsum += p;                                                                \
        }                                                                             \
        unsigned int d0, d1, d2, d3, d4, d5, d6, d7;                                  \
        asm("v_cvt_pk_bf16_f32 %0, %1, %2" : "=v"(d0) : "v"(st[0]),  "v"(st[1]));     \
        asm("v_cvt_pk_bf16_f32 %0, %1, %2" : "=v"(d1) : "v"(st[2]),  "v"(st[3]));     \
        asm("v_cvt_pk_bf16_f32 %0, %1, %2" : "=v"(d2) : "v"(st[4]),  "v"(st[5]));     \
        asm("v_cvt_pk_bf16_f32 %0, %1, %2" : "=v"(d3) : "v"(st[6]),  "v"(st[7]));     \
        asm("v_cvt_pk_bf16_f32 %0, %1, %2" : "=v"(d4) : "v"(st[8]),  "v"(st[9]));     \
        asm("v_cvt_pk_bf16_f32 %0, %1, %2" : "=v"(d5) : "v"(st[10]), "v"(st[11]));    \
        asm("v_cvt_pk_bf16_f32 %0, %1, %2" : "=v"(d6) : "v"(st[12]), "v"(st[13]));    \
        asm("v_cvt_pk_bf16_f32 %0, %1, %2" : "=v"(d7) : "v"(st[14]), "v"(st[15]));    \
        asm("v_permlane32_swap_b32 %0, %1" : "+v"(d0), "+v"(d2));                     \
        asm("v_permlane32_swap_b32 %0, %1" : "+v"(d1), "+v"(d3));                     \
        asm("v_permlane32_swap_b32 %0, %1" : "+v"(d4), "+v"(d6));                     \
        asm("v_permlane32_swap_b32 %0, %1" : "+v"(d5), "+v"(d7));                     \
        union { unsigned int u[4]; bf16x8 v; } pa0, pa1;                              \
        pa0.u[0] = d0; pa0.u[1] = d1; pa0.u[2] = d2; pa0.u[3] = d3;                   \
        pa1.u[0] = d4; pa1.u[1] = d5; pa1.u[2] = d6; pa1.u[3] = d7;                   \
        o0 = __builtin_amdgcn_mfma_f32_32x32x16_bf16(pa0.v, V0, o0, 0, 0, 0);         \
        o1 = __builtin_amdgcn_mfma_f32_32x32x16_bf16(pa0.v, V1, o1, 0, 0, 0);         \
        o0 = __builtin_amdgcn_mfma_f32_32x32x16_bf16(pa1.v, V2, o0, 0, 0, 0);         \
        o1 = __builtin_amdgcn_mfma_f32_32x32x16_bf16(pa1.v, V3, o1, 0, 0, 0);         \
    }

    LOADT(aK0, aK1, aK2, aK3, aV0, aV1, aV2, aV3);

    const int NT = SEQ / 64;   // 32, even
    for (int t = 0; t < NT; t += 2) {
        LOADT(bK0, bK1, bK2, bK3, bV0, bV1, bV2, bV3);
        COMPUTE(aK0, aK1, aK2, aK3, aV0, aV1, aV2, aV3);
        if (t + 2 < NT)
            LOADT(aK0, aK1, aK2, aK3, aV0, aV1, aV2, aV3);
        COMPUTE(bK0, bK1, bK2, bK3, bV0, bV1, bV2, bV3);
    }
#undef LOADT
#undef COMPUTE

    // ---- merge kh partials + normalize + store ----
    rsum += __shfl_xor(rsum, 32);
    if (kh == 1) {
#pragma unroll
        for (int r = 0; r < 16; ++r) {
            int q = (r & 3) + 8 * (r >> 2) + 4 * hi;
            red[(qh * 32 + q) * 64 + l31]      = o0[r];
            red[(qh * 32 + q) * 64 + 32 + l31] = o1[r];
        }
    }
    if (lane < 32) rsb[(kh * 2 + qh) * 32 + l31] = rsum;
    __syncthreads();
    if (kh == 0) {
#pragma unroll
        for (int r = 0; r < 16; ++r) {
            int q = (r & 3) + 8 * (r >> 2) + 4 * hi;
            float tot = rsb[qh * 32 + q] + rsb[(2 + qh) * 32 + q];
            float inv = 1.0f / tot;
            float v0e = (o0[r] + red[(qh * 32 + q) * 64 + l31]) * inv;
            float v1e = (o1[r] + red[(qh * 32 + q) * 64 + 32 + l31]) * inv;
            int row = qbase + qh * 32 + q;
            attn[(size_t)row * (HEADS * QDIM) + h * QDIM + l31]      = f2bf(v0e);
            attn[(size_t)row * (HEADS * QDIM) + h * QDIM + 32 + l31] = f2bf(v1e);
        }
    }
}

extern "C" void kernel_launch(void* const* d_in, const int* in_sizes, int n_in,
                              void* d_out, int out_size, void* d_ws, size_t ws_size,
                              hipStream_t stream) {
    const float* xi = (const float*)d_in[0];
    const float* Wq = (const float*)d_in[1];
    const float* bq = (const float*)d_in[2];
    const float* Wk = (const float*)d_in[3];
    const float* bk = (const float*)d_in[4];
    const float* Wv = (const float*)d_in[5];
    const float* bv = (const float*)d_in[6];
    const float* Wo = (const float*)d_in[7];
    const float* bo = (const float*)d_in[8];

    unsigned short* xi_bf = (unsigned short*)d_ws;
    unsigned short* WcatT = xi_bf + (size_t)M_ROWS * D_MODEL;
    unsigned short* WoT   = WcatT + (size_t)NCAT * D_MODEL;
    float*          bcat  = (float*)(WoT + (size_t)D_MODEL * D_MODEL);
    unsigned short* qkvc  = (unsigned short*)(bcat + NCAT);
    unsigned short* kfrag = qkvc + (size_t)M_ROWS * NCAT;
    unsigned short* vfrag = kfrag + (size_t)BATCH * HEADS * 32 * 4096;
    unsigned short* attnb = vfrag + (size_t)BATCH * HEADS * 32 * 4096;

    // fold softmax scale AND log2(e) into Q projection (attn uses exp2)
    float qscale = 1.4426950408889634f / sqrtf((float)SEQ);

    k_prep_w<<<3072, 256, 0, stream>>>(xi, Wq, Wk, Wv, bq, bk, bv, Wo,
                                       xi_bf, WcatT, bcat, WoT, qscale);

    k_gemm<true><<<dim3(NCAT / 128, M_ROWS / 128), 256, 0, stream>>>(
        xi_bf, WcatT, bcat, (void*)qkvc, kfrag, vfrag, NCAT, D_MODEL);

    k_attn<<<BATCH * HEADS * (SEQ / 64), 256, 0, stream>>>(qkvc, kfrag, vfrag, attnb);

    k_gemm<false><<<dim3(D_MODEL / 128, M_ROWS / 128), 256, 0, stream>>>(
        attnb, WoT, bo, d_out, nullptr, nullptr, D_MODEL, D_MODEL);
}